// Round 3
// baseline (131.140 us; speedup 1.0000x reference)
//
#include <hip/hip_runtime.h>
#include <math.h>

#define N_NODES 1024
#define F_DIM   128
#define M_DIM   256
#define E_DIM   8
#define P_PAIRS 523776   // N*(N-1)/2
#define NBLK    1056     // sum_{tj=0..31} (2*tj+2) 16x32 tiles
#define APITCH  33       // padded row pitch in float4 (bank-decorrelating)
#define WPITCH  36       // kA W1-tile row pitch in dwords (32 k + 4 pad, 16B-aligned, bank-balanced)

typedef float v2f __attribute__((ext_vector_type(2)));

// ---------- Kernel A (R19 rewrite): coalesced W1, 8 nodes/block ----------
// Old kA read W1 per-thread-row straight from global: every wave load touched
// 64 distinct cache lines (uncoalesced, TA-serialized, ~1 block/CU -> no TLP
// cover). New: 128 blocks x 8 nodes; W1 staged in k-chunks [256 m x 32 k]
// with fully-coalesced float4 global loads into LDS (pitch 36 dwords:
// 16B-aligned rows, bank-balanced 8-start pattern ~ same class as kC's
// APITCH-33 reads that measure 0 conflicts). Compute: thread t owns m=t,
// reads its W-row chunk back as 8 conflict-balanced ds_read_b128; x enters
// via wave-uniform loads (s_load path, no DS/VALU cost). FMA chain per
// output is k-ascending with x,y,z,w order inside each float4 -- identical
// sequence to the old kernel -> bit-exact (absmax 0 preserved).
__global__ __launch_bounds__(256) void kA(const float* __restrict__ x,
                                          const float* __restrict__ ctx,
                                          const float* __restrict__ W1,
                                          const float* __restrict__ b1,
                                          const float* __restrict__ gamma,
                                          const float* __restrict__ beta,
                                          const float* __restrict__ rmean,
                                          const float* __restrict__ rvar,
                                          const float* __restrict__ W2,
                                          const float* __restrict__ b2,
                                          float* __restrict__ pa,
                                          float* __restrict__ pb,
                                          float* __restrict__ stress,
                                          float* __restrict__ w2ft,
                                          float* __restrict__ b2f) {
  const int t = threadIdx.x;

  if (blockIdx.x == 128) {   // BN fold + b2 fold block
    __shared__ float bnbs[256];
    const float s   = gamma[t] / sqrtf(rvar[t] + 1e-5f);
    bnbs[t] = beta[t] - s * rmean[t];
    #pragma unroll
    for (int e = 0; e < 8; ++e) w2ft[t * 8 + e] = W2[e * 256 + t] * s;
    __syncthreads();
    const int wv = t >> 6, lane = t & 63;
    #pragma unroll
    for (int r = 0; r < 2; ++r) {
      const int e = wv * 2 + r;
      float acc = 0.f;
      #pragma unroll
      for (int k = 0; k < 4; ++k) acc += W2[e * 256 + lane + 64 * k] * bnbs[lane + 64 * k];
      #pragma unroll
      for (int m = 32; m > 0; m >>= 1) acc += __shfl_xor(acc, m, 64);
      if (lane == 0) b2f[e] = acc + b2[e];
    }
    return;
  }

  __shared__ float wt[256 * WPITCH];   // 36.0 KB: one 256x32 W1 k-chunk
  __shared__ float xv[8][128];         // 4 KB: this block's 8 x-rows (stress only)
  const int n0 = blockIdx.x * 8;

  // stage xv (coalesced, 1 float4/thread) + W1 chunk 0
  {
    const int row = t >> 5, c4 = t & 31;
    *(float4*)&xv[row][c4 * 4] = ((const float4*)(x + (size_t)(n0 + row) * F_DIM))[c4];
  }
  {
    const int r = t >> 3, c4 = t & 7;   // with q merged below: rows q*32 + (t>>3)
    #pragma unroll
    for (int q = 0; q < 8; ++q) {
      const int rr = q * 32 + r;
      *(float4*)&wt[rr * WPITCH + c4 * 4] =
          ((const float4*)W1)[(size_t)rr * 65 + c4];   // chunk 0: cols 0..31
    }
  }
  __syncthreads();

  // stress for the 8 nodes (2 per wave, sequential -- same math as before)
  {
    const int wv = t >> 6, lane = t & 63;
    #pragma unroll
    for (int s2 = 0; s2 < 2; ++s2) {
      const int n = wv * 2 + s2;
      const float a = xv[n][lane], b = xv[n][lane + 64];
      float sum = a + b;
      #pragma unroll
      for (int m = 32; m > 0; m >>= 1) sum += __shfl_xor(sum, m, 64);
      const float mean = sum * (1.0f / 128.0f);
      const float d0 = a - mean, d1 = b - mean;
      float ss = d0 * d0 + d1 * d1;
      #pragma unroll
      for (int m = 32; m > 0; m >>= 1) ss += __shfl_xor(ss, m, 64);
      if (lane == 0) stress[n0 + n] = sqrtf(ss * (1.0f / 127.0f));
    }
  }

  float accA[8] = {0.f,0.f,0.f,0.f,0.f,0.f,0.f,0.f};
  float accB[8] = {0.f,0.f,0.f,0.f,0.f,0.f,0.f,0.f};

  // 8 chunks of 32 k: c 0..3 -> A-weights (cols c*32..), c 4..7 -> B (cols 128+..)
  for (int c = 0; c < 8; ++c) {
    // compute current chunk
    {
      const int kbase = (c & 3) * 32;          // x k-range for this chunk
      float4 wreg[8];
      #pragma unroll
      for (int k4 = 0; k4 < 8; ++k4) wreg[k4] = *(const float4*)&wt[t * WPITCH + k4 * 4];
      float* acc = (c < 4) ? accA : accB;
      #pragma unroll
      for (int k4 = 0; k4 < 8; ++k4) {
        const float4 w4 = wreg[k4];
        #pragma unroll
        for (int nn = 0; nn < 8; ++nn) {
          const float* xr = x + (size_t)(n0 + nn) * F_DIM + kbase + k4 * 4;  // wave-uniform
          acc[nn] = fmaf(xr[3], w4.w, fmaf(xr[2], w4.z, fmaf(xr[1], w4.y, fmaf(xr[0], w4.x, acc[nn]))));
        }
      }
    }
    if (c < 7) {
      __syncthreads();   // all reads of wt done
      const int r = t >> 3, c4 = t & 7;
      const int coff4 = (c + 1 < 4) ? (c + 1) * 8 : 32 + (c + 1 - 4) * 8;  // col offset in float4
      #pragma unroll
      for (int q = 0; q < 8; ++q) {
        const int rr = q * 32 + r;
        *(float4*)&wt[rr * WPITCH + c4 * 4] =
            ((const float4*)W1)[(size_t)rr * 65 + coff4 + c4];
      }
      __syncthreads();   // chunk c+1 visible
    }
  }

  // ctx fold + writes (same expressions as before -> bit-exact)
  const float c0 = ctx[0], c1 = ctx[1], c2 = ctx[2], c3 = ctx[3];
  const float* rowt = W1 + (size_t)t * 260 + 256;
  const float ctv = b1[t] + c0 * rowt[0] + c1 * rowt[1] + c2 * rowt[2] + c3 * rowt[3];
  #pragma unroll
  for (int nn = 0; nn < 8; ++nn) {
    pa[(size_t)(n0 + nn) * M_DIM + t] = accA[nn] + ctv;
    pb[(size_t)(n0 + nn) * M_DIM + t] = accB[nn];
  }
}

// ---------- Kernel C: 1056 triangular 16x32 tiles, 256 threads, 2 pairs/thread ----------
// R19: byte-identical revert to the R16 form (measured 41.7-41.9 us).
// R17 (sw pipeline) was a no-op: compiler already schedules this. R18
// (4 pairs/thread, 128 thr) regressed: wall tracks wave residency, and
// 2 pairs/thread at 256 thr x 1056 blocks is the occupancy-optimal point
// (523776 pairs / 262144 threads = 2).
__global__ __launch_bounds__(256, 6) void kC(const float* __restrict__ pa,
                                             const float* __restrict__ pb,
                                             const float* __restrict__ w2ft,
                                             const float* __restrict__ b2f,
                                             const float* __restrict__ W3,
                                             const float* __restrict__ b3,
                                             const float* __restrict__ stress,
                                             float* __restrict__ out) {
  __shared__ float4 a4[16 * APITCH];   // 16 i-rows, 128-m chunk, pitch 33
  __shared__ float4 b4[32 * APITCH];   // 32 j-rows
  const int t = threadIdx.x;

  // decode p -> (tj, si): p = tj*(tj+1) + si, si in [0, 2*tj+2)
  const int p = blockIdx.x;
  int tj = (int)((sqrtf(4.0f * (float)p + 1.0f) - 1.0f) * 0.5f);
  while ((tj + 1) * (tj + 2) <= p) ++tj;
  while (tj * (tj + 1) > p) --tj;
  const int si = p - tj * (tj + 1);
  const int i0 = si * 16, j0 = tj * 32;

  const float4* pa4 = (const float4*)pa;
  const float4* pb4 = (const float4*)pb;
  const double* wdp = (const double*)w2ft;   // row m: 4 doubles = e-pairs

  // ---- chunk-0 staging loads issued; stress-mean computed under their latency ----
  float4 rA[2], rB[4];
  #pragma unroll
  for (int q = 0; q < 2; ++q) {
    const int d = q * 256 + t, r = d >> 5, c = d & 31;
    rA[q] = pa4[(size_t)(i0 + r) * 64 + c];
  }
  #pragma unroll
  for (int q = 0; q < 4; ++q) {
    const int d = q * 256 + t, r = d >> 5, c = d & 31;
    rB[q] = pb4[(size_t)(j0 + r) * 64 + c];
  }

  float ssum = 0.f;
  {
    const int lane = t & 63;
    #pragma unroll
    for (int k = 0; k < 16; ++k) ssum += stress[lane + 64 * k];
    #pragma unroll
    for (int m = 32; m > 0; m >>= 1) ssum += __shfl_xor(ssum, m, 64);
  }
  const float smean = ssum * (1.0f / 1024.0f);

  // ---- write chunk-0 tiles (transient regs die here; no spill risk) ----
  #pragma unroll
  for (int q = 0; q < 2; ++q) {
    const int d = q * 256 + t, r = d >> 5, c = d & 31;
    a4[r * APITCH + c] = rA[q];
  }
  #pragma unroll
  for (int q = 0; q < 4; ++q) {
    const int d = q * 256 + t, r = d >> 5, c = d & 31;
    b4[r * APITCH + c] = rB[q];
  }
  __syncthreads();

  const int jx = t & 15;   // j pair: jx, jx+16
  const int iy = t >> 4;   // i within tile, 0..15
  v2f acc[8];              // per e: {acc for j=jx, acc for j=jx+16}
  #pragma unroll
  for (int e = 0; e < 8; ++e) acc[e] = (v2f){0.f, 0.f};

  const float4* aRow  = a4 + iy * APITCH;          // bases hoisted; m4 offsets immediate
  const float4* bRow0 = b4 + jx * APITCH;
  const float4* bRow1 = b4 + (jx + 16) * APITCH;

  auto computeChunk = [&](int cw) {
    #pragma unroll 2
    for (int m4 = 0; m4 < 32; ++m4) {
      const float4 A  = aRow[m4];
      const float4 B0 = bRow0[m4];
      const float4 B1 = bRow1[m4];
      const double* wr = wdp + (size_t)(cw + m4) * 16;   // 4 m x 4 e-pair doubles
      const float* Af  = (const float*)&A;
      const float* B0f = (const float*)&B0;
      const float* B1f = (const float*)&B1;
      #pragma unroll
      for (int mm = 0; mm < 4; ++mm) {
        v2f R;
        R.x = fmaxf(Af[mm] + B0f[mm], 0.f);   // r for (i, jx)
        R.y = fmaxf(Af[mm] + B1f[mm], 0.f);   // r for (i, jx+16)
        #pragma unroll
        for (int k = 0; k < 4; ++k) {
          const double wp = wr[mm * 4 + k];   // {w[m][2k], w[m][2k+1]} in SGPR pair
          // even e = 2k: broadcast LO word of wp to both halves (R9-proven form)
          asm("v_pk_fma_f32 %0, %1, %2, %0 op_sel:[0,0,0] op_sel_hi:[0,1,1]"
              : "+v"(acc[2 * k]) : "s"(wp), "v"(R));
          // odd e = 2k+1: broadcast HI word of wp to both halves
          asm("v_pk_fma_f32 %0, %1, %2, %0 op_sel:[1,0,0] op_sel_hi:[1,1,1]"
              : "+v"(acc[2 * k + 1]) : "s"(wp), "v"(R));
        }
      }
    }
  };

  computeChunk(0);
  __syncthreads();

  // ---- stage chunk 1 (transient regs again) ----
  #pragma unroll
  for (int q = 0; q < 2; ++q) {
    const int d = q * 256 + t, r = d >> 5, c = d & 31;
    rA[q] = pa4[(size_t)(i0 + r) * 64 + 32 + c];
  }
  #pragma unroll
  for (int q = 0; q < 4; ++q) {
    const int d = q * 256 + t, r = d >> 5, c = d & 31;
    rB[q] = pb4[(size_t)(j0 + r) * 64 + 32 + c];
  }
  #pragma unroll
  for (int q = 0; q < 2; ++q) {
    const int d = q * 256 + t, r = d >> 5, c = d & 31;
    a4[r * APITCH + c] = rA[q];
  }
  #pragma unroll
  for (int q = 0; q < 4; ++q) {
    const int d = q * 256 + t, r = d >> 5, c = d & 31;
    b4[r * APITCH + c] = rB[q];
  }
  __syncthreads();

  computeChunk(32);

  // ---- epilogue ----
  float w3v[8], b2v[8];
  #pragma unroll
  for (int e = 0; e < 8; ++e) { w3v[e] = W3[e]; b2v[e] = b2f[e]; }
  const float b3v = b3[0];
  const int i = i0 + iy;
  #pragma unroll
  for (int jb = 0; jb < 2; ++jb) {
    const int j = j0 + jx + jb * 16;
    if (i < j) {
      float logit = b3v;
      #pragma unroll
      for (int e = 0; e < 8; ++e) {
        const float av = jb ? acc[e].y : acc[e].x;
        const float h2 = fmaxf(av + b2v[e], 0.f);
        logit = fmaf(w3v[e], h2, logit);
      }
      const float score = 1.0f / (1.0f + expf(-logit));
      const int idx = i * 1023 - (i * (i - 1)) / 2 + (j - i - 1);
      out[idx] = score;
      const bool mk = (score > 0.5f) && (stress[i] > smean) && (stress[j] > smean);
      out[P_PAIRS + idx] = mk ? 1.0f : 0.0f;
    }
  }
}

extern "C" void kernel_launch(void* const* d_in, const int* in_sizes, int n_in,
                              void* d_out, int out_size, void* d_ws, size_t ws_size,
                              hipStream_t stream) {
  const float* x     = (const float*)d_in[0];
  const float* ctx   = (const float*)d_in[1];
  const float* W1    = (const float*)d_in[2];
  const float* b1    = (const float*)d_in[3];
  const float* gamma = (const float*)d_in[4];
  const float* beta  = (const float*)d_in[5];
  const float* rmean = (const float*)d_in[6];
  const float* rvar  = (const float*)d_in[7];
  const float* W2    = (const float*)d_in[8];
  const float* b2    = (const float*)d_in[9];
  const float* W3    = (const float*)d_in[10];
  const float* b3    = (const float*)d_in[11];
  float* out = (float*)d_out;

  float* ws     = (float*)d_ws;
  float* pa     = ws;              // 1024*256 (cterm pre-folded)
  float* pb     = pa + 262144;     // 1024*256
  float* w2ft   = pb + 262144;     // 256*8 (transposed [m][e], BN-scaled)
  float* b2f    = w2ft + 2048;     // 8
  float* stress = b2f + 8;         // 1024

  hipLaunchKernelGGL(kA, dim3(129), dim3(256), 0, stream, x, ctx, W1, b1, gamma, beta,
                     rmean, rvar, W2, b2, pa, pb, stress, w2ft, b2f);
  hipLaunchKernelGGL(kC, dim3(NBLK), dim3(256), 0, stream, pa, pb, w2ft, b2f,
                     W3, b3, stress, out);
}